// Round 15
// baseline (327.050 us; speedup 1.0000x reference)
//
#include <hip/hip_runtime.h>
#include <math.h>

typedef unsigned short ushort_t;
typedef unsigned int uint_t;
typedef __attribute__((ext_vector_type(8))) short bf16x8;
typedef __attribute__((ext_vector_type(16))) float f32x16;

// Problem constants
constexpr int Bc   = 8;
constexpr int Nn   = 4500;
constexpr int Ec   = 72000;
constexpr int D    = 128;
constexpr int T    = Bc * Nn;      // 36000
constexpr int TE   = Bc * Ec;      // 576000
constexpr float EPS = 1e-5f;

constexpr int PAD = 32;            // ints per counter line (128B)
constexpr int RST = 64;            // edata slots per node

// Persistent-kernel geometry: 768 blocks x 256 thr, >=3 blocks/CU co-resident
constexpr int GRID = 768;
constexpr int NTHR = 256;
constexpr int BPB  = GRID / 8;     // 96 blocks per batch (XCD-pinned phases)

// Workspace layout (bytes)
constexpr size_t WS_CNTP  = 0;          // T*PAD i32 = 4,608,000
constexpr size_t WS_EDATA = 4608000;    // T*RST u32 = 9,216,000
constexpr size_t WS_DINV  = 13824000;   // T f32 = 144,000
constexpr size_t WS_WHI   = 13968000;   // 128*128 bf16
constexpr size_t WS_WLO   = 14000768;   // 128*128 bf16
constexpr size_t WS_H     = 14033536;   // T*D bf16 = 9,216,000
constexpr size_t WS_BAR   = 23249664;   // 3 i32 barrier slots (zeroed per call)

__device__ __forceinline__ ushort_t f32_to_bf16_rne(float f) {
  uint_t u = __float_as_uint(f);
  uint_t r = (u + 0x7fffu + ((u >> 16) & 1u)) >> 16;
  return (ushort_t)r;
}
__device__ __forceinline__ float bf16_to_f32(ushort_t h) {
  return __uint_as_float(((uint_t)h) << 16);
}

// Device-scope grid barrier: one-shot slot (pre-zeroed), arrive + spin.
// __threadfence() = agent acq/rel -> L2 writeback/invalidate on gfx950,
// making ordinary stores visible across XCDs (same mechanism as grid.sync()).
__device__ __forceinline__ void gbar(int* slot) {
  __syncthreads();
  if (threadIdx.x == 0) {
    __threadfence();                 // release: flush this XCD's dirty lines
    atomicAdd(slot, 1);
    while (__hip_atomic_load(slot, __ATOMIC_RELAXED,
                             __HIP_MEMORY_SCOPE_AGENT) < GRID)
      __builtin_amdgcn_s_sleep(8);   // backoff: don't hammer the fabric
    __threadfence();                 // acquire: invalidate stale L1/L2
  }
  __syncthreads();
}

// ---------------------------------------------------------------------------
// Single persistent kernel, 4 phases, 3 grid barriers.
// ---------------------------------------------------------------------------
__global__ __launch_bounds__(NTHR, 3) void fused_kernel(
    const float* __restrict__ x, const int* __restrict__ ei,
    const float* __restrict__ nmask, const float* __restrict__ emask,
    const float* __restrict__ W, const float* __restrict__ bias,
    const float* __restrict__ gamma, const float* __restrict__ beta,
    int* __restrict__ cntp, uint_t* __restrict__ edata,
    float* __restrict__ dinv, ushort_t* __restrict__ Whi,
    ushort_t* __restrict__ Wlo, ushort_t* __restrict__ h,
    int* __restrict__ bar, float* __restrict__ out) {
  const int bid = blockIdx.x;
  const int tid = threadIdx.x;
  const int gidf = bid * NTHR + tid;          // flat id, < 196608

  // ---- Phase A: W -> bf16 hi/lo split; zero cntp -------------------------
  if (gidf < D * D) {
    float w = W[gidf];
    ushort_t hi = f32_to_bf16_rne(w);
    Whi[gidf] = hi;
    Wlo[gidf] = f32_to_bf16_rne(w - bf16_to_f32(hi));
  }
  {
    int4* cntp4 = (int4*)cntp;
    for (int i = gidf; i < T * PAD / 4; i += GRID * NTHR)
      cntp4[i] = make_int4(0, 0, 0, 0);
  }
  gbar(bar + 0);

  // ---- Phase B: GEMM (independent of edges) then edge pass ---------------
  {
    const int lane = tid & 63;
    const int r  = lane & 31;
    const int kh = lane >> 5;
    for (int g = bid * 4 + (tid >> 6); g < (T / 32) * 4; g += GRID * 4) {
      const int mt = g >> 2;               // row-tile (block's 4 waves share it)
      const int ct = g & 3;                // col-tile (32 cols)
      const int m0 = mt * 32;
      const float* xrow = x + (size_t)(m0 + r) * D + kh * 8;

      f32x16 acc;
#pragma unroll
      for (int j = 0; j < 16; ++j) acc[j] = 0.f;

#pragma unroll
      for (int ks = 0; ks < 8; ++ks) {
        const float4 p0 = ((const float4*)(xrow + ks * 16))[0];
        const float4 p1 = ((const float4*)(xrow + ks * 16))[1];
        const float xa[8] = {p0.x, p0.y, p0.z, p0.w, p1.x, p1.y, p1.z, p1.w};
        bf16x8 ahi, alo;
#pragma unroll
        for (int j = 0; j < 8; ++j) {
          ushort_t hb = f32_to_bf16_rne(xa[j]);
          ahi[j] = (short)hb;
          alo[j] = (short)f32_to_bf16_rne(xa[j] - bf16_to_f32(hb));
        }
        const size_t boff = (size_t)(ct * 32 + r) * D + ks * 16 + kh * 8;
        bf16x8 bhi = *(const bf16x8*)(Whi + boff);
        bf16x8 blo = *(const bf16x8*)(Wlo + boff);
        acc = __builtin_amdgcn_mfma_f32_32x32x16_bf16(ahi, bhi, acc, 0, 0, 0);
        acc = __builtin_amdgcn_mfma_f32_32x32x16_bf16(ahi, blo, acc, 0, 0, 0);
        acc = __builtin_amdgcn_mfma_f32_32x32x16_bf16(alo, bhi, acc, 0, 0, 0);
      }

      const int col = ct * 32 + r;
      const float bv = bias[col];
#pragma unroll
      for (int j = 0; j < 16; ++j) {
        const int mrow = m0 + (j & 3) + 8 * (j >> 2) + 4 * kh;
        h[(size_t)mrow * D + col] = f32_to_bf16_rne(acc[j] + bv);
      }
    }
  }
  {
    // Edge pass, XCD-pinned: blocks with bid&7==b handle batch b.
    const int b = bid & 7;
    const int* eb = ei + b * 2 * Ec;
    for (int el = (bid >> 3) * NTHR + tid; el < Ec; el += BPB * NTHR) {
      int t0 = eb[Ec + el];
      if ((unsigned)t0 >= (unsigned)Nn) continue;   // defensive
      int tg = t0 + b * Nn;
      int rk = atomicAdd(&cntp[(size_t)tg * PAD], 1);
      if (rk >= RST) continue;                      // defensive (P ~ 0)
      int s0 = eb[el];
      float ew = emask[b * Ec + el];
      uint_t sl = (uint_t)s0;
      if ((unsigned)s0 >= (unsigned)Nn) { sl = 0; ew = 0.f; }
      edata[(size_t)tg * RST + rk] =
          ((uint_t)f32_to_bf16_rne(ew) << 16) | sl;
    }
  }
  gbar(bar + 1);

  // ---- Phase C: dinv = 1/sqrt(deg+1) (XCD-pinned row-walk) ---------------
  {
    const int b = bid & 7;
    for (int nl = (bid >> 3) * NTHR + tid; nl < Nn; nl += BPB * NTHR) {
      const int i = b * Nn + nl;
      int cnt = cntp[(size_t)i * PAD];
      cnt = (cnt > RST) ? RST : cnt;
      const uint_t* row = edata + (size_t)i * RST;
      float s = 0.f;
      for (int j = 0; j < cnt; ++j) s += bf16_to_f32((ushort_t)(row[j] >> 16));
      dinv[i] = 1.0f / sqrtf(s + 1.0f);
    }
  }
  gbar(bar + 2);

  // ---- Phase D: gather + residual + LayerNorm + ReLU + mask --------------
  {
    const int lane = tid & 63;
    const int f4   = lane & 31;
    const int half = lane >> 5;
    const int wid  = tid >> 6;
    const ushort4* h4 = (const ushort4*)h;

    for (int gg = bid; gg < T / 4; gg += GRID) {    // gg&7 == bid&7: pinned
      const int b    = gg & 7;
      const int node = b * Nn + (gg >> 3) * 4 + wid;
      const int bOff = b * Nn;

      int cnt = cntp[(size_t)node * PAD];
      cnt = (cnt > RST) ? RST : cnt;
      const uint_t* row = edata + (size_t)node * RST;

      ushort4 hq = h4[(size_t)node * 32 + f4];
      float4 hv = make_float4(bf16_to_f32(hq.x), bf16_to_f32(hq.y),
                              bf16_to_f32(hq.z), bf16_to_f32(hq.w));

      float4 accE = make_float4(0.f, 0.f, 0.f, 0.f);
      int i = half;
      for (; i + 6 < cnt; i += 8) {
        uint_t p0 = row[i];
        uint_t p1 = row[i + 2];
        uint_t p2 = row[i + 4];
        uint_t p3 = row[i + 6];
        int sg0 = bOff + (p0 & 0xFFFFu);
        int sg1 = bOff + (p1 & 0xFFFFu);
        int sg2 = bOff + (p2 & 0xFFFFu);
        int sg3 = bOff + (p3 & 0xFFFFu);
        float c0 = dinv[sg0] * bf16_to_f32((ushort_t)(p0 >> 16));
        float c1 = dinv[sg1] * bf16_to_f32((ushort_t)(p1 >> 16));
        float c2 = dinv[sg2] * bf16_to_f32((ushort_t)(p2 >> 16));
        float c3 = dinv[sg3] * bf16_to_f32((ushort_t)(p3 >> 16));
        ushort4 q0 = h4[(size_t)sg0 * 32 + f4];
        ushort4 q1 = h4[(size_t)sg1 * 32 + f4];
        ushort4 q2 = h4[(size_t)sg2 * 32 + f4];
        ushort4 q3 = h4[(size_t)sg3 * 32 + f4];
        accE.x += bf16_to_f32(q0.x) * c0 + bf16_to_f32(q1.x) * c1 +
                  bf16_to_f32(q2.x) * c2 + bf16_to_f32(q3.x) * c3;
        accE.y += bf16_to_f32(q0.y) * c0 + bf16_to_f32(q1.y) * c1 +
                  bf16_to_f32(q2.y) * c2 + bf16_to_f32(q3.y) * c3;
        accE.z += bf16_to_f32(q0.z) * c0 + bf16_to_f32(q1.z) * c1 +
                  bf16_to_f32(q2.z) * c2 + bf16_to_f32(q3.z) * c3;
        accE.w += bf16_to_f32(q0.w) * c0 + bf16_to_f32(q1.w) * c1 +
                  bf16_to_f32(q2.w) * c2 + bf16_to_f32(q3.w) * c3;
      }
      for (; i < cnt; i += 2) {
        uint_t p0 = row[i];
        int sg0 = bOff + (p0 & 0xFFFFu);
        float c0 = dinv[sg0] * bf16_to_f32((ushort_t)(p0 >> 16));
        ushort4 q0 = h4[(size_t)sg0 * 32 + f4];
        accE.x += bf16_to_f32(q0.x) * c0;
        accE.y += bf16_to_f32(q0.y) * c0;
        accE.z += bf16_to_f32(q0.z) * c0;
        accE.w += bf16_to_f32(q0.w) * c0;
      }

      accE.x += __shfl_xor(accE.x, 32);
      accE.y += __shfl_xor(accE.y, 32);
      accE.z += __shfl_xor(accE.z, 32);
      accE.w += __shfl_xor(accE.w, 32);

      const float dt = dinv[node];
      float4 acc;
      acc.x = hv.x * (1.f + dt) + dt * accE.x;
      acc.y = hv.y * (1.f + dt) + dt * accE.y;
      acc.z = hv.z * (1.f + dt) + dt * accE.z;
      acc.w = hv.w * (1.f + dt) + dt * accE.w;

      float su = acc.x + acc.y + acc.z + acc.w;
      float ss = acc.x * acc.x + acc.y * acc.y + acc.z * acc.z + acc.w * acc.w;
#pragma unroll
      for (int o = 16; o > 0; o >>= 1) {
        su += __shfl_xor(su, o);
        ss += __shfl_xor(ss, o);
      }
      float mu  = su * (1.0f / 128.0f);
      float var = ss * (1.0f / 128.0f) - mu * mu;
      float rs  = 1.0f / sqrtf(var + EPS);
      float m   = nmask[node];

      float4 g  = ((const float4*)gamma)[f4];
      float4 bb = ((const float4*)beta)[f4];
      float4 rv;
      rv.x = fmaxf((acc.x - mu) * rs * g.x + bb.x, 0.f) * m;
      rv.y = fmaxf((acc.y - mu) * rs * g.y + bb.y, 0.f) * m;
      rv.z = fmaxf((acc.z - mu) * rs * g.z + bb.z, 0.f) * m;
      rv.w = fmaxf((acc.w - mu) * rs * g.w + bb.w, 0.f) * m;
      if (half == 0) ((float4*)out)[(size_t)node * 32 + f4] = rv;
    }
  }
}

// ---------------------------------------------------------------------------
extern "C" void kernel_launch(void* const* d_in, const int* in_sizes, int n_in,
                              void* d_out, int out_size, void* d_ws, size_t ws_size,
                              hipStream_t stream) {
  const float* x     = (const float*)d_in[0];
  const int*   ei    = (const int*)d_in[1];
  const float* nmask = (const float*)d_in[2];
  const float* emask = (const float*)d_in[3];
  const float* W     = (const float*)d_in[4];
  const float* bias  = (const float*)d_in[5];
  const float* gamma = (const float*)d_in[6];
  const float* beta  = (const float*)d_in[7];
  float* out = (float*)d_out;

  char*     ws    = (char*)d_ws;
  int*      cntp  = (int*)     (ws + WS_CNTP);
  uint_t*   edata = (uint_t*)  (ws + WS_EDATA);
  float*    dinv  = (float*)   (ws + WS_DINV);
  ushort_t* Whi   = (ushort_t*)(ws + WS_WHI);
  ushort_t* Wlo   = (ushort_t*)(ws + WS_WLO);
  ushort_t* h     = (ushort_t*)(ws + WS_H);
  int*      bar   = (int*)     (ws + WS_BAR);

  // Zero the 3 barrier slots every call (ws poison persists otherwise).
  hipMemsetAsync(bar, 0, 128, stream);
  fused_kernel<<<GRID, NTHR, 0, stream>>>(x, ei, nmask, emask, W, bias,
                                          gamma, beta, cntp, edata, dinv,
                                          Whi, Wlo, h, bar, out);
}

// Round 16
// 82.449 us; speedup vs baseline: 3.9667x; 3.9667x over previous
//
#include <hip/hip_runtime.h>
#include <math.h>

typedef unsigned short ushort_t;
typedef unsigned int uint_t;
typedef __attribute__((ext_vector_type(8))) short bf16x8;
typedef __attribute__((ext_vector_type(16))) float f32x16;

// Problem constants (from reference)
constexpr int Bc   = 8;
constexpr int Nn   = 4500;
constexpr int Ec   = 72000;
constexpr int D    = 128;          // IN_DIM == OUT_DIM == 128
constexpr int T    = Bc * Nn;      // 36000 total nodes
constexpr int TE   = Bc * Ec;      // 576000 total edges
constexpr float EPS = 1e-5f;

constexpr int PAD = 32;            // ints per counter line (128B)
constexpr int RST = 64;            // edata slots per node (max deg ~45), 4B each

// Prep zones: W split | cntp zero
constexpr int NB_W    = 64;                    // 16384 W elems / 256
constexpr int NB_Z    = (T * PAD / 4) / 256;   // 1125 (int4 zero)
constexpr int NB_PREP = NB_W + NB_Z;           // 1189

// Edge pass: XCD-pinned, 8 batches x 282 chunks
constexpr int NB_ECH  = (Ec + 255) / 256;      // 282
constexpr int NB_EDGE = 8 * NB_ECH;            // 2256

// gemm+dinv zones. GEMM XCD-pinned: 8 batches x 141 tile-slots (3 idle).
constexpr int NB_GEMMP = 8 * 141;                 // 1128
constexpr int NB_DINV  = 8 * 18;                  // 144 (XCD-pinned)
constexpr int NB_GD    = NB_GEMMP + NB_DINV;      // 1272

// Workspace layout (bytes), ~23.3 MB total.
constexpr size_t WS_CNTP  = 0;            // T*PAD i32 = 4,608,000
constexpr size_t WS_EDATA = 4608000;      // T*RST u32 = 9,216,000
constexpr size_t WS_DINV  = 13824000;     // T f32 = 144,000
constexpr size_t WS_WHI   = 13968000;     // 128*128 bf16 = 32,768
constexpr size_t WS_WLO   = 14000768;     // 128*128 bf16 = 32,768
constexpr size_t WS_H     = 14033536;     // T*D bf16 = 9,216,000

__device__ __forceinline__ ushort_t f32_to_bf16_rne(float f) {
  uint_t u = __float_as_uint(f);
  uint_t r = (u + 0x7fffu + ((u >> 16) & 1u)) >> 16;
  return (ushort_t)r;
}
__device__ __forceinline__ float bf16_to_f32(ushort_t h) {
  return __uint_as_float(((uint_t)h) << 16);
}

// ---------------------------------------------------------------------------
// Prep (zoned): [0,64) W -> bf16 hi/lo; [64,1189) zero cntp (int4).
// ---------------------------------------------------------------------------
__global__ __launch_bounds__(256) void prep_kernel(
    const float* __restrict__ W, ushort_t* __restrict__ Whi,
    ushort_t* __restrict__ Wlo, int4* __restrict__ cntp4) {
  const int bid = blockIdx.x;
  if (bid < NB_W) {
    int i = bid * 256 + threadIdx.x;
    float w = W[i];
    ushort_t hi = f32_to_bf16_rne(w);
    Whi[i] = hi;
    Wlo[i] = f32_to_bf16_rne(w - bf16_to_f32(hi));
  } else {
    int i = (bid - NB_W) * 256 + threadIdx.x;
    cntp4[i] = make_int4(0, 0, 0, 0);
  }
}

// ---------------------------------------------------------------------------
// Edge pass (XCD-pinned: bid&7 = batch): rk = fetch-add on padded counter;
// packed placement edata[tgt*RST+rk] = bf16(ew)<<16 | src_local (4B).
// ---------------------------------------------------------------------------
__global__ __launch_bounds__(256) void edge_kernel(
    const int* __restrict__ ei, const float* __restrict__ em,
    int* __restrict__ cntp, uint_t* __restrict__ edata) {
  const int b  = blockIdx.x & 7;
  const int el = (blockIdx.x >> 3) * 256 + threadIdx.x;
  if (el >= Ec) return;
  const int* eb = ei + b * 2 * Ec;
  int t0 = eb[Ec + el];
  if ((unsigned)t0 >= (unsigned)Nn) return;     // defensive
  int tg = t0 + b * Nn;
  int rk = atomicAdd(&cntp[(size_t)tg * PAD], 1);
  if (rk >= RST) return;                        // defensive (P ~ 0)
  int s0 = eb[el];
  float ew = em[b * Ec + el];
  uint_t sl = (uint_t)s0;
  if ((unsigned)s0 >= (unsigned)Nn) { sl = 0; ew = 0.f; }
  uint_t pk = ((uint_t)f32_to_bf16_rne(ew) << 16) | sl;
  edata[(size_t)tg * RST + rk] = pk;
}

// ---------------------------------------------------------------------------
// Zone-merged: [0,1128) XCD-pinned MFMA GEMM; [1128,1272) dinv (XCD-pinned).
// GEMM pinning: tiles partitioned by batch via c(b) = round(b*1125/8);
// bid = q*8 + b so bid&7 = batch -> h rows for batch b are produced on the
// SAME XCD that gather_ln (also pinned) consumes them on; h slice (1.15MB
// bf16) stays in that XCD's write-back L2 across the kernel boundary.
// Block = one 32-row tile; 4 waves = 4 col-quarters; 24 MFMAs/wave.
// A/B frag: elem = lane&31, k = 8*(lane>>5)+j. C/D: col = lane&31,
// row = (j&3)+8*(j>>2)+4*(lane>>5).
// ---------------------------------------------------------------------------
__global__ __launch_bounds__(256) void gemm_dinv_kernel(
    const float* __restrict__ x, const ushort_t* __restrict__ Whi,
    const ushort_t* __restrict__ Wlo, const float* __restrict__ bias,
    ushort_t* __restrict__ h, const uint_t* __restrict__ edata,
    const int* __restrict__ cntp, float* __restrict__ dinv) {
  const int bid = blockIdx.x;
  if (bid < NB_GEMMP) {
    const int b = bid & 7;
    const int q = bid >> 3;
    const int ct0 = (b * 1125 + 4) >> 3;            // c(b)
    const int ct1 = ((b + 1) * 1125 + 4) >> 3;      // c(b+1)
    if (q >= ct1 - ct0) return;                     // 3 idle blocks
    const int mt = ct0 + q;
    const int m0 = mt * 32;
    const int ct = threadIdx.x >> 6;                // col-quarter
    const int lane = threadIdx.x & 63;
    const int r  = lane & 31;
    const int kh = lane >> 5;

    const float* xrow = x + (size_t)(m0 + r) * D + kh * 8;

    f32x16 acc;
#pragma unroll
    for (int j = 0; j < 16; ++j) acc[j] = 0.f;

#pragma unroll
    for (int ks = 0; ks < 8; ++ks) {
      const float4 p0 = ((const float4*)(xrow + ks * 16))[0];
      const float4 p1 = ((const float4*)(xrow + ks * 16))[1];
      const float xa[8] = {p0.x, p0.y, p0.z, p0.w, p1.x, p1.y, p1.z, p1.w};
      bf16x8 ahi, alo;
#pragma unroll
      for (int j = 0; j < 8; ++j) {
        ushort_t hb = f32_to_bf16_rne(xa[j]);
        ahi[j] = (short)hb;
        alo[j] = (short)f32_to_bf16_rne(xa[j] - bf16_to_f32(hb));
      }
      const size_t boff = (size_t)(ct * 32 + r) * D + ks * 16 + kh * 8;
      bf16x8 bhi = *(const bf16x8*)(Whi + boff);
      bf16x8 blo = *(const bf16x8*)(Wlo + boff);
      acc = __builtin_amdgcn_mfma_f32_32x32x16_bf16(ahi, bhi, acc, 0, 0, 0);
      acc = __builtin_amdgcn_mfma_f32_32x32x16_bf16(ahi, blo, acc, 0, 0, 0);
      acc = __builtin_amdgcn_mfma_f32_32x32x16_bf16(alo, bhi, acc, 0, 0, 0);
    }

    const int col = ct * 32 + r;
    const float bv = bias[col];
#pragma unroll
    for (int j = 0; j < 16; ++j) {
      const int mrow = m0 + (j & 3) + 8 * (j >> 2) + 4 * kh;
      h[(size_t)mrow * D + col] = f32_to_bf16_rne(acc[j] + bv);
    }
  } else {
    // dinv zone, XCD-pinned: batch = (bid-NB_GEMMP)&7
    const int zb = bid - NB_GEMMP;
    const int b  = zb & 7;
    const int nl = (zb >> 3) * 256 + threadIdx.x;
    if (nl >= Nn) return;
    const int i = b * Nn + nl;
    int cnt = cntp[(size_t)i * PAD];
    cnt = (cnt > RST) ? RST : cnt;
    const uint_t* row = edata + (size_t)i * RST;
    float s = 0.f;
    for (int j = 0; j < cnt; ++j) s += bf16_to_f32((ushort_t)(row[j] >> 16));
    dinv[i] = 1.0f / sqrtf(s + 1.0f);
  }
}

// ---------------------------------------------------------------------------
// Fused gather + residual + LayerNorm + ReLU + mask (packed edata, bf16 h).
// XCD-pinned: bid%8 = batch (h slice 1.15MB -> per-XCD L2, now produced on
// the same XCD by the pinned GEMM). 32 lanes x 4 features per row; lane-half
// processes alternating slots; fold shfl_xor(32).
// ---------------------------------------------------------------------------
__global__ __launch_bounds__(256) void gather_ln_kernel(
    const ushort_t* __restrict__ h, const int* __restrict__ cntp,
    const uint_t* __restrict__ edata, const float* __restrict__ dinv,
    const float* __restrict__ gamma, const float* __restrict__ beta,
    const float* __restrict__ mask, float* __restrict__ out) {
  const int bid  = blockIdx.x;                  // 9000 = 8 * 1125
  const int b    = bid & 7;
  const int wid  = threadIdx.x >> 6;
  const int node = b * Nn + (bid >> 3) * 4 + wid;
  const int bOff = b * Nn;
  const int lane = threadIdx.x & 63;
  const int f4   = lane & 31;
  const int half = lane >> 5;

  const ushort4* h4 = (const ushort4*)h;
  int cnt = cntp[(size_t)node * PAD];
  cnt = (cnt > RST) ? RST : cnt;
  const uint_t* row = edata + (size_t)node * RST;

  ushort4 hq = h4[(size_t)node * 32 + f4];
  float4 hv = make_float4(bf16_to_f32(hq.x), bf16_to_f32(hq.y),
                          bf16_to_f32(hq.z), bf16_to_f32(hq.w));

  float4 accE = make_float4(0.f, 0.f, 0.f, 0.f);
  int i = half;
  for (; i + 6 < cnt; i += 8) {
    uint_t p0 = row[i];
    uint_t p1 = row[i + 2];
    uint_t p2 = row[i + 4];
    uint_t p3 = row[i + 6];
    int sg0 = bOff + (p0 & 0xFFFFu);
    int sg1 = bOff + (p1 & 0xFFFFu);
    int sg2 = bOff + (p2 & 0xFFFFu);
    int sg3 = bOff + (p3 & 0xFFFFu);
    float c0 = dinv[sg0] * bf16_to_f32((ushort_t)(p0 >> 16));
    float c1 = dinv[sg1] * bf16_to_f32((ushort_t)(p1 >> 16));
    float c2 = dinv[sg2] * bf16_to_f32((ushort_t)(p2 >> 16));
    float c3 = dinv[sg3] * bf16_to_f32((ushort_t)(p3 >> 16));
    ushort4 q0 = h4[(size_t)sg0 * 32 + f4];
    ushort4 q1 = h4[(size_t)sg1 * 32 + f4];
    ushort4 q2 = h4[(size_t)sg2 * 32 + f4];
    ushort4 q3 = h4[(size_t)sg3 * 32 + f4];
    accE.x += bf16_to_f32(q0.x) * c0 + bf16_to_f32(q1.x) * c1 +
              bf16_to_f32(q2.x) * c2 + bf16_to_f32(q3.x) * c3;
    accE.y += bf16_to_f32(q0.y) * c0 + bf16_to_f32(q1.y) * c1 +
              bf16_to_f32(q2.y) * c2 + bf16_to_f32(q3.y) * c3;
    accE.z += bf16_to_f32(q0.z) * c0 + bf16_to_f32(q1.z) * c1 +
              bf16_to_f32(q2.z) * c2 + bf16_to_f32(q3.z) * c3;
    accE.w += bf16_to_f32(q0.w) * c0 + bf16_to_f32(q1.w) * c1 +
              bf16_to_f32(q2.w) * c2 + bf16_to_f32(q3.w) * c3;
  }
  for (; i < cnt; i += 2) {
    uint_t p0 = row[i];
    int sg0 = bOff + (p0 & 0xFFFFu);
    float c0 = dinv[sg0] * bf16_to_f32((ushort_t)(p0 >> 16));
    ushort4 q0 = h4[(size_t)sg0 * 32 + f4];
    accE.x += bf16_to_f32(q0.x) * c0;
    accE.y += bf16_to_f32(q0.y) * c0;
    accE.z += bf16_to_f32(q0.z) * c0;
    accE.w += bf16_to_f32(q0.w) * c0;
  }

  accE.x += __shfl_xor(accE.x, 32);
  accE.y += __shfl_xor(accE.y, 32);
  accE.z += __shfl_xor(accE.z, 32);
  accE.w += __shfl_xor(accE.w, 32);

  const float dt = dinv[node];
  float4 acc;
  acc.x = hv.x * (1.f + dt) + dt * accE.x;
  acc.y = hv.y * (1.f + dt) + dt * accE.y;
  acc.z = hv.z * (1.f + dt) + dt * accE.z;
  acc.w = hv.w * (1.f + dt) + dt * accE.w;

  float su = acc.x + acc.y + acc.z + acc.w;
  float ss = acc.x * acc.x + acc.y * acc.y + acc.z * acc.z + acc.w * acc.w;
#pragma unroll
  for (int o = 16; o > 0; o >>= 1) {
    su += __shfl_xor(su, o);
    ss += __shfl_xor(ss, o);
  }
  float mu  = su * (1.0f / 128.0f);
  float var = ss * (1.0f / 128.0f) - mu * mu;
  float rs  = 1.0f / sqrtf(var + EPS);
  float m   = mask[node];

  float4 g  = ((const float4*)gamma)[f4];
  float4 bb = ((const float4*)beta)[f4];
  float4 rv;
  rv.x = fmaxf((acc.x - mu) * rs * g.x + bb.x, 0.f) * m;
  rv.y = fmaxf((acc.y - mu) * rs * g.y + bb.y, 0.f) * m;
  rv.z = fmaxf((acc.z - mu) * rs * g.z + bb.z, 0.f) * m;
  rv.w = fmaxf((acc.w - mu) * rs * g.w + bb.w, 0.f) * m;
  if (half == 0) ((float4*)out)[(size_t)node * 32 + f4] = rv;
}

// ---------------------------------------------------------------------------
extern "C" void kernel_launch(void* const* d_in, const int* in_sizes, int n_in,
                              void* d_out, int out_size, void* d_ws, size_t ws_size,
                              hipStream_t stream) {
  const float* x     = (const float*)d_in[0];
  const int*   ei    = (const int*)d_in[1];
  const float* nmask = (const float*)d_in[2];
  const float* emask = (const float*)d_in[3];
  const float* W     = (const float*)d_in[4];
  const float* bias  = (const float*)d_in[5];
  const float* gamma = (const float*)d_in[6];
  const float* beta  = (const float*)d_in[7];
  float* out = (float*)d_out;

  char*     ws    = (char*)d_ws;
  int*      cntp  = (int*)     (ws + WS_CNTP);
  uint_t*   edata = (uint_t*)  (ws + WS_EDATA);
  float*    dinv  = (float*)   (ws + WS_DINV);
  ushort_t* Whi   = (ushort_t*)(ws + WS_WHI);
  ushort_t* Wlo   = (ushort_t*)(ws + WS_WLO);
  ushort_t* h     = (ushort_t*)(ws + WS_H);

  prep_kernel<<<NB_PREP, 256, 0, stream>>>(W, Whi, Wlo, (int4*)cntp);
  edge_kernel<<<NB_EDGE, 256, 0, stream>>>(ei, emask, cntp, edata);
  gemm_dinv_kernel<<<NB_GD, 256, 0, stream>>>(x, Whi, Wlo, bias, h,
                                              edata, cntp, dinv);
  gather_ln_kernel<<<T / 4, 256, 0, stream>>>(h, cntp, edata, dinv,
                                              gamma, beta, nmask, out);
}